// Round 6
// baseline (518.738 us; speedup 1.0000x reference)
//
#include <hip/hip_runtime.h>
#include <math.h>

#define B_ 2
#define S_ 2048
#define E_ 1024
#define H_ 16
#define D_ 64
#define M_ (B_*S_)

typedef short bf16x8 __attribute__((ext_vector_type(8)));
typedef float f32x4 __attribute__((ext_vector_type(4)));
typedef unsigned short u16x4 __attribute__((ext_vector_type(4)));

__device__ __forceinline__ unsigned short f2bf(float f) {
    unsigned int u = __builtin_bit_cast(unsigned int, f);
    u += 0x7FFFu + ((u >> 16) & 1u);
    return (unsigned short)(u >> 16);
}
__device__ __forceinline__ f32x4 mfma16(bf16x8 a, bf16x8 b, f32x4 c) {
    return __builtin_amdgcn_mfma_f32_16x16x32_bf16(a, b, c, 0, 0, 0);
}
// load 8 consecutive f32 -> bf16x8 (RNE)
__device__ __forceinline__ bf16x8 cvt8(const float* p) {
    f32x4 lo = *(const f32x4*)p;
    f32x4 hi = *(const f32x4*)(p + 4);
    bf16x8 r;
#pragma unroll
    for (int e = 0; e < 4; e++) { r[e] = (short)f2bf(lo[e]); r[e + 4] = (short)f2bf(hi[e]); }
    return r;
}

// ---------------- Kernel 1: QKV projection + RoPE (z = 0:Q, 1:K, 2:V) -------
// C = X(4096x1024,f32) @ W^T + b.  Q,K: RoPE then (B,H,S,D) bf16.  V: (B,H,D,S) bf16.
// Epilogue stages the 128x128 tile in LDS so global stores are 128B-coalesced.
__global__ __launch_bounds__(256, 2) void qkv_rope_kernel(
    const float* __restrict__ X,
    const float* __restrict__ Wq, const float* __restrict__ Wk,
    const float* __restrict__ Wv,
    const float* __restrict__ bq, const float* __restrict__ bk,
    const float* __restrict__ bv,
    unsigned short* __restrict__ Qo, unsigned short* __restrict__ Ko,
    unsigned short* __restrict__ Vo)
{
    __shared__ unsigned short As[128 * 32];
    __shared__ unsigned short Bs[128 * 32];
    __shared__ unsigned short Cs[128 * 132];   // output staging, pitch 132 (8B-aligned rows)
    const int t = threadIdx.x;
    const int w = t >> 6, lane = t & 63, quad = lane >> 4, l16 = lane & 15;
    const int wr = (w >> 1) * 64, wc = (w & 1) * 64;
    const int n0 = blockIdx.x * 128, m0 = blockIdx.y * 128;
    const int z = blockIdx.z;
    const float* W    = (z == 0) ? Wq : (z == 1) ? Wk : Wv;
    const float* bias = (z == 0) ? bq : (z == 1) ? bk : bv;

    const int r4 = t >> 2, c8 = (t & 3) * 8;
    const float* Ag = X + (size_t)(m0 + r4) * E_ + c8;
    const float* Bg = W + (size_t)(n0 + r4) * E_ + c8;

    f32x4 zero = {0.f, 0.f, 0.f, 0.f};
    f32x4 acc[4][4];
#pragma unroll
    for (int i = 0; i < 4; i++)
#pragma unroll
        for (int j = 0; j < 4; j++) acc[i][j] = zero;

    for (int kt = 0; kt < E_; kt += 32) {
        bf16x8 a0 = cvt8(Ag + kt);
        bf16x8 a1 = cvt8(Ag + 64 * E_ + kt);
        bf16x8 b0 = cvt8(Bg + kt);
        bf16x8 b1 = cvt8(Bg + 64 * E_ + kt);
        __syncthreads();
        *(bf16x8*)&As[t * 8]        = a0;
        *(bf16x8*)&As[t * 8 + 2048] = a1;
        *(bf16x8*)&Bs[t * 8]        = b0;
        *(bf16x8*)&Bs[t * 8 + 2048] = b1;
        __syncthreads();
        bf16x8 af[4], bfr[4];
#pragma unroll
        for (int i = 0; i < 4; i++)
            af[i] = *(const bf16x8*)&As[(wr + i * 16 + l16) * 32 + quad * 8];
#pragma unroll
        for (int j = 0; j < 4; j++)
            bfr[j] = *(const bf16x8*)&Bs[(wc + j * 16 + l16) * 32 + quad * 8];
#pragma unroll
        for (int i = 0; i < 4; i++)
#pragma unroll
            for (int j = 0; j < 4; j++)
                acc[i][j] = mfma16(af[i], bfr[j], acc[i][j]);
    }

    const int seg = quad;          // 0..3: (seg>>1)=row within wave-pair, (seg&1)=128B half
    if (z < 2) {
        // ---- RoPE in-register, stage [m_local][n_local] ----
        const float C = -0.41524101186091903f;  // -log2(10000)/32
#pragma unroll
        for (int j = 0; j < 4; j++) {
            int n_local = wc + j * 16 + l16;
            int n = n0 + n_local;
            int d = n & 63, f = d >> 1;
            float inv = exp2f(C * (float)f);
            float bvv = bias[n];
            float sgn = (d & 1) ? 1.f : -1.f;
#pragma unroll
            for (int i = 0; i < 4; i++) {
                int mb = wr + i * 16 + quad * 4;
#pragma unroll
                for (int r = 0; r < 4; r++) {
                    int m = m0 + mb + r;
                    int s = m & (S_ - 1);
                    float val = acc[i][j][r] + bvv;
                    float oth = __shfl_xor(val, 1);
                    float ang = (float)s * inv;
                    float sn = sinf(ang);
                    float cs = cosf(ang);
                    Cs[(mb + r) * 132 + n_local] = f2bf(val * cs + sgn * oth * sn);
                }
            }
        }
        __syncthreads();
        // ---- coalesced write-out: 16 lanes x u16x4 = 128B per (row, half) ----
        unsigned short* Out = (z == 0) ? Qo : Ko;
        const int btok = m0 >> 11;
        const int half = seg & 1;
#pragma unroll
        for (int it = 0; it < 16; it++) {
            int m_local = it * 8 + w * 2 + (seg >> 1);
            int s = (m0 + m_local) & (S_ - 1);
            int h = (n0 + half * 64) >> 6;
            u16x4 v = *(const u16x4*)&Cs[m_local * 132 + half * 64 + l16 * 4];
            *(u16x4*)&Out[(((size_t)btok * H_ + h) * S_ + s) * D_ + l16 * 4] = v;
        }
    } else {
        // ---- stage transposed [n_local][m_local] for (B,H,D,S) layout ----
#pragma unroll
        for (int j = 0; j < 4; j++) {
            int n_local = wc + j * 16 + l16;
            float bvv = bias[n0 + n_local];
#pragma unroll
            for (int i = 0; i < 4; i++) {
                int mb = wr + i * 16 + quad * 4;
#pragma unroll
                for (int r = 0; r < 4; r++)
                    Cs[n_local * 132 + mb + r] = f2bf(acc[i][j][r] + bvv);
            }
        }
        __syncthreads();
        const int btok = m0 >> 11;
        const int s0 = m0 & (S_ - 1);
        const int half = seg & 1;
#pragma unroll
        for (int it = 0; it < 16; it++) {
            int n_local = it * 8 + w * 2 + (seg >> 1);
            int n = n0 + n_local;
            int h = n >> 6, d = n & 63;
            u16x4 v = *(const u16x4*)&Cs[n_local * 132 + half * 64 + l16 * 4];
            *(u16x4*)&Vo[(((size_t)btok * H_ + h) * D_ + d) * S_ + s0 + half * 64 + l16 * 4] = v;
        }
    }
}

// ---------------- Kernel 2: attention (no-max softmax, flash-style) ---------
__global__ __launch_bounds__(256, 2) void attn_kernel(
    const unsigned short* __restrict__ Q, const unsigned short* __restrict__ K,
    const unsigned short* __restrict__ Vt, unsigned short* __restrict__ ctx)
{
    __shared__ unsigned short Ks[2][64 * 32];
    __shared__ unsigned short Vs[2][64 * 32];
    __shared__ unsigned short Ps[4][32 * 72];
    const int t = threadIdx.x;
    const int w = t >> 6, lane = t & 63, quad = lane >> 4, l16 = lane & 15;
    const int bh = blockIdx.y;
    const int q0 = blockIdx.x * 128 + w * 32;

    const unsigned short* Qg = Q + ((size_t)bh * S_ + q0) * D_;
    bf16x8 qf[2][2];
#pragma unroll
    for (int i = 0; i < 2; i++)
#pragma unroll
        for (int ks = 0; ks < 2; ks++)
            qf[i][ks] = *(const bf16x8*)(Qg + (i * 16 + l16) * 64 + ks * 32 + quad * 8);

    bf16x8 ones;
#pragma unroll
    for (int e = 0; e < 8; e++) ones[e] = (short)0x3F80;

    f32x4 zero = {0.f, 0.f, 0.f, 0.f};
    f32x4 acc_o[2][4];
    f32x4 acc_l[2];
#pragma unroll
    for (int i = 0; i < 2; i++) {
        acc_l[i] = zero;
#pragma unroll
        for (int j = 0; j < 4; j++) acc_o[i][j] = zero;
    }

    const int r4 = t >> 2, c8v = (t & 3) * 8;
    const unsigned short* Kg0 = K + (size_t)bh * S_ * D_;
    const unsigned short* Vg0 = Vt + (size_t)bh * D_ * S_;

    for (int kt = 0; kt < S_; kt += 64) {
        const unsigned short* Kg = Kg0 + (size_t)(kt + r4) * 64 + c8v;
        const unsigned short* Vg = Vg0 + (size_t)r4 * S_ + kt + c8v;
        bf16x8 k0 = *(const bf16x8*)(Kg);
        bf16x8 k1 = *(const bf16x8*)(Kg + 32);
        bf16x8 v0 = *(const bf16x8*)(Vg);
        bf16x8 v1 = *(const bf16x8*)(Vg + 32);
        __syncthreads();
        *(bf16x8*)&Ks[0][t * 8] = k0;
        *(bf16x8*)&Ks[1][t * 8] = k1;
        *(bf16x8*)&Vs[0][t * 8] = v0;
        *(bf16x8*)&Vs[1][t * 8] = v1;
        __syncthreads();

        f32x4 sc[2][4];
#pragma unroll
        for (int i = 0; i < 2; i++)
#pragma unroll
            for (int j = 0; j < 4; j++) sc[i][j] = zero;
#pragma unroll
        for (int ks = 0; ks < 2; ks++) {
            bf16x8 kf[4];
#pragma unroll
            for (int j = 0; j < 4; j++)
                kf[j] = *(const bf16x8*)&Ks[ks][(j * 16 + l16) * 32 + quad * 8];
#pragma unroll
            for (int i = 0; i < 2; i++)
#pragma unroll
                for (int j = 0; j < 4; j++)
                    sc[i][j] = mfma16(qf[i][ks], kf[j], sc[i][j]);
        }
#pragma unroll
        for (int i = 0; i < 2; i++)
#pragma unroll
            for (int j = 0; j < 4; j++)
#pragma unroll
                for (int r = 0; r < 4; r++) {
                    float p = __expf(sc[i][j][r] * 0.125f);
                    Ps[w][(i * 16 + quad * 4 + r) * 72 + j * 16 + l16] = f2bf(p);
                }
        __syncthreads();
#pragma unroll
        for (int ks = 0; ks < 2; ks++) {
            bf16x8 pf[2], vf[4];
#pragma unroll
            for (int i = 0; i < 2; i++)
                pf[i] = *(const bf16x8*)&Ps[w][(i * 16 + l16) * 72 + ks * 32 + quad * 8];
#pragma unroll
            for (int jd = 0; jd < 4; jd++)
                vf[jd] = *(const bf16x8*)&Vs[ks][(jd * 16 + l16) * 32 + quad * 8];
#pragma unroll
            for (int i = 0; i < 2; i++) {
#pragma unroll
                for (int jd = 0; jd < 4; jd++)
                    acc_o[i][jd] = mfma16(pf[i], vf[jd], acc_o[i][jd]);
                acc_l[i] = mfma16(pf[i], ones, acc_l[i]);
            }
        }
    }

    const int b = bh >> 4, h = bh & 15;
#pragma unroll
    for (int i = 0; i < 2; i++) {
        f32x4 rl;
#pragma unroll
        for (int r = 0; r < 4; r++) rl[r] = 1.0f / acc_l[i][r];
#pragma unroll
        for (int jd = 0; jd < 4; jd++)
#pragma unroll
            for (int r = 0; r < 4; r++) {
                int qrow = q0 + i * 16 + quad * 4 + r;
                int col = h * 64 + jd * 16 + l16;
                ctx[((size_t)b * S_ + qrow) * E_ + col] = f2bf(acc_o[i][jd][r] * rl[r]);
            }
    }
}

// ---------------- Kernel 3: output projection (f32 W/bias, f32 out) ---------
__global__ __launch_bounds__(256, 2) void out_kernel(
    const unsigned short* __restrict__ Cx, const float* __restrict__ Wo,
    const float* __restrict__ bo, float* __restrict__ out)
{
    __shared__ unsigned short As[128 * 32];
    __shared__ unsigned short Bs[64 * 32];
    const int t = threadIdx.x;
    const int w = t >> 6, lane = t & 63, quad = lane >> 4, l16 = lane & 15;
    const int m0 = blockIdx.y * 128, n0 = blockIdx.x * 64;
    const int wr = w * 32;
    const int r4 = t >> 2, c8 = (t & 3) * 8;
    const unsigned short* Ag = Cx + (size_t)(m0 + r4) * E_ + c8;
    const float*          Bg = Wo + (size_t)(n0 + (r4 & 63)) * E_ + c8;

    f32x4 zero = {0.f, 0.f, 0.f, 0.f};
    f32x4 acc[2][4];
#pragma unroll
    for (int i = 0; i < 2; i++)
#pragma unroll
        for (int j = 0; j < 4; j++) acc[i][j] = zero;

    for (int kt = 0; kt < E_; kt += 32) {
        bf16x8 a0 = *(const bf16x8*)(Ag + kt);
        bf16x8 a1 = *(const bf16x8*)(Ag + 64 * E_ + kt);
        bf16x8 b0 = cvt8(Bg + kt);
        __syncthreads();
        *(bf16x8*)&As[t * 8]        = a0;
        *(bf16x8*)&As[t * 8 + 2048] = a1;
        *(bf16x8*)&Bs[t * 8]        = b0;
        __syncthreads();
        bf16x8 af[2], bfr[4];
#pragma unroll
        for (int i = 0; i < 2; i++)
            af[i] = *(const bf16x8*)&As[(wr + i * 16 + l16) * 32 + quad * 8];
#pragma unroll
        for (int j = 0; j < 4; j++)
            bfr[j] = *(const bf16x8*)&Bs[(j * 16 + l16) * 32 + quad * 8];
#pragma unroll
        for (int i = 0; i < 2; i++)
#pragma unroll
            for (int j = 0; j < 4; j++)
                acc[i][j] = mfma16(af[i], bfr[j], acc[i][j]);
    }

#pragma unroll
    for (int j = 0; j < 4; j++) {
        int n = n0 + j * 16 + l16;
        float bvv = bo[n];
#pragma unroll
        for (int i = 0; i < 2; i++) {
            int mrow = m0 + wr + i * 16 + quad * 4;
#pragma unroll
            for (int r = 0; r < 4; r++)
                out[(size_t)(mrow + r) * E_ + n] = acc[i][j][r] + bvv;
        }
    }
}

extern "C" void kernel_launch(void* const* d_in, const int* in_sizes, int n_in,
                              void* d_out, int out_size, void* d_ws, size_t ws_size,
                              hipStream_t stream) {
    const float* X  = (const float*)d_in[0];
    const float* Wq = (const float*)d_in[1];
    const float* bq = (const float*)d_in[2];
    const float* Wk = (const float*)d_in[3];
    const float* bk = (const float*)d_in[4];
    const float* Wv = (const float*)d_in[5];
    const float* bv = (const float*)d_in[6];
    const float* Wo = (const float*)d_in[7];
    const float* bo = (const float*)d_in[8];
    float* outp = (float*)d_out;

    const size_t TN = (size_t)B_ * H_ * S_ * D_;  // 4M elements
    if (ws_size < 4 * TN * sizeof(unsigned short)) return;

    unsigned short* Qb = (unsigned short*)d_ws;
    unsigned short* Kb = Qb + TN;
    unsigned short* Vb = Kb + TN;
    unsigned short* Cx = Vb + TN;

    qkv_rope_kernel<<<dim3(E_ / 128, M_ / 128, 3), 256, 0, stream>>>(
        X, Wq, Wk, Wv, bq, bk, bv, Qb, Kb, Vb);
    attn_kernel<<<dim3(S_ / 128, B_ * H_), 256, 0, stream>>>(Qb, Kb, Vb, Cx);
    out_kernel<<<dim3(E_ / 64, M_ / 128), 256, 0, stream>>>(Cx, Wo, bo, outp);
}

// Round 7
// 220.464 us; speedup vs baseline: 2.3529x; 2.3529x over previous
//
#include <hip/hip_runtime.h>
#include <math.h>

#define B_ 2
#define S_ 2048
#define E_ 1024
#define H_ 16
#define D_ 64
#define M_ (B_*S_)

typedef short bf16x8 __attribute__((ext_vector_type(8)));
typedef float f32x4 __attribute__((ext_vector_type(4)));
typedef unsigned short u16x4 __attribute__((ext_vector_type(4)));

__device__ __forceinline__ unsigned short f2bf(float f) {
    unsigned int u = __builtin_bit_cast(unsigned int, f);
    u += 0x7FFFu + ((u >> 16) & 1u);
    return (unsigned short)(u >> 16);
}
__device__ __forceinline__ f32x4 mfma16(bf16x8 a, bf16x8 b, f32x4 c) {
    return __builtin_amdgcn_mfma_f32_16x16x32_bf16(a, b, c, 0, 0, 0);
}
// load 8 consecutive f32 -> bf16x8 (RNE)
__device__ __forceinline__ bf16x8 cvt8(const float* p) {
    f32x4 lo = *(const f32x4*)p;
    f32x4 hi = *(const f32x4*)(p + 4);
    bf16x8 r;
#pragma unroll
    for (int e = 0; e < 4; e++) { r[e] = (short)f2bf(lo[e]); r[e + 4] = (short)f2bf(hi[e]); }
    return r;
}

// ---------------- Kernel 1: QKV projection + RoPE (z = 0:Q, 1:K, 2:V) -------
// C = X(4096x1024,f32) @ W^T + b.  Q,K: RoPE then (B,H,S,D) bf16.  V: (B,H,D,S) bf16.
// LDS: As/Bs (16 KB) unioned with epilogue staging Cs (33 KB) -> 33 KB total,
// 3 blocks/CU with __launch_bounds__(256,3) for latency hiding.
__global__ __launch_bounds__(256, 3) void qkv_rope_kernel(
    const float* __restrict__ X,
    const float* __restrict__ Wq, const float* __restrict__ Wk,
    const float* __restrict__ Wv,
    const float* __restrict__ bq, const float* __restrict__ bk,
    const float* __restrict__ bv,
    unsigned short* __restrict__ Qo, unsigned short* __restrict__ Ko,
    unsigned short* __restrict__ Vo)
{
    __shared__ __align__(16) unsigned char lds_raw[128 * 132 * 2];  // 33792 B
    unsigned short* As = (unsigned short*)lds_raw;                  // 8 KB
    unsigned short* Bs = (unsigned short*)(lds_raw + 8192);         // 8 KB
    unsigned short* Cs = (unsigned short*)lds_raw;                  // full (epilogue only)

    const int t = threadIdx.x;
    const int w = t >> 6, lane = t & 63, quad = lane >> 4, l16 = lane & 15;
    const int wr = (w >> 1) * 64, wc = (w & 1) * 64;
    const int n0 = blockIdx.x * 128, m0 = blockIdx.y * 128;
    const int z = blockIdx.z;
    const float* W    = (z == 0) ? Wq : (z == 1) ? Wk : Wv;
    const float* bias = (z == 0) ? bq : (z == 1) ? bk : bv;

    const int r4 = t >> 2, c8 = (t & 3) * 8;
    const float* Ag = X + (size_t)(m0 + r4) * E_ + c8;
    const float* Bg = W + (size_t)(n0 + r4) * E_ + c8;

    f32x4 zero = {0.f, 0.f, 0.f, 0.f};
    f32x4 acc[4][4];
#pragma unroll
    for (int i = 0; i < 4; i++)
#pragma unroll
        for (int j = 0; j < 4; j++) acc[i][j] = zero;

    for (int kt = 0; kt < E_; kt += 32) {
        bf16x8 a0 = cvt8(Ag + kt);
        bf16x8 a1 = cvt8(Ag + 64 * E_ + kt);
        bf16x8 b0 = cvt8(Bg + kt);
        bf16x8 b1 = cvt8(Bg + 64 * E_ + kt);
        __syncthreads();
        *(bf16x8*)&As[t * 8]        = a0;
        *(bf16x8*)&As[t * 8 + 2048] = a1;
        *(bf16x8*)&Bs[t * 8]        = b0;
        *(bf16x8*)&Bs[t * 8 + 2048] = b1;
        __syncthreads();
        bf16x8 af[4], bfr[4];
#pragma unroll
        for (int i = 0; i < 4; i++)
            af[i] = *(const bf16x8*)&As[(wr + i * 16 + l16) * 32 + quad * 8];
#pragma unroll
        for (int j = 0; j < 4; j++)
            bfr[j] = *(const bf16x8*)&Bs[(wc + j * 16 + l16) * 32 + quad * 8];
#pragma unroll
        for (int i = 0; i < 4; i++)
#pragma unroll
            for (int j = 0; j < 4; j++)
                acc[i][j] = mfma16(af[i], bfr[j], acc[i][j]);
    }

    __syncthreads();   // As/Bs dead; Cs (aliased) comes alive
    const int seg = quad;
    if (z < 2) {
        // ---- RoPE in-register (hw sin/cos, revolution domain), stage tile ----
        const float C = -0.41524101186091903f;     // -log2(10000)/32
        const float INV2PI = 0.15915494309189535f; // 1/(2*pi)
#pragma unroll
        for (int j = 0; j < 4; j++) {
            int n_local = wc + j * 16 + l16;
            int n = n0 + n_local;
            int d = n & 63, f = d >> 1;
            float inv_rev = exp2f(C * (float)f) * INV2PI;
            float bvv = bias[n];
            float sgn = (d & 1) ? 1.f : -1.f;
#pragma unroll
            for (int i = 0; i < 4; i++) {
                int mb = wr + i * 16 + quad * 4;
#pragma unroll
                for (int r = 0; r < 4; r++) {
                    int m = m0 + mb + r;
                    int s = m & (S_ - 1);
                    float val = acc[i][j][r] + bvv;
                    float oth = __shfl_xor(val, 1);
                    float rev = (float)s * inv_rev;
                    float fr = rev - rintf(rev);       // [-0.5, 0.5] revolutions
                    float sn = __builtin_amdgcn_sinf(fr);
                    float cs = __builtin_amdgcn_cosf(fr);
                    Cs[(mb + r) * 132 + n_local] = f2bf(val * cs + sgn * oth * sn);
                }
            }
        }
        __syncthreads();
        // ---- coalesced write-out: 16 lanes x u16x4 = 128B per (row, half) ----
        unsigned short* Out = (z == 0) ? Qo : Ko;
        const int btok = m0 >> 11;
        const int half = seg & 1;
#pragma unroll
        for (int it = 0; it < 16; it++) {
            int m_local = it * 8 + w * 2 + (seg >> 1);
            int s = (m0 + m_local) & (S_ - 1);
            int h = (n0 + half * 64) >> 6;
            u16x4 v = *(const u16x4*)&Cs[m_local * 132 + half * 64 + l16 * 4];
            *(u16x4*)&Out[(((size_t)btok * H_ + h) * S_ + s) * D_ + l16 * 4] = v;
        }
    } else {
        // ---- stage transposed [n_local][m_local] for (B,H,D,S) layout ----
#pragma unroll
        for (int j = 0; j < 4; j++) {
            int n_local = wc + j * 16 + l16;
            float bvv = bias[n0 + n_local];
#pragma unroll
            for (int i = 0; i < 4; i++) {
                int mb = wr + i * 16 + quad * 4;
#pragma unroll
                for (int r = 0; r < 4; r++)
                    Cs[n_local * 132 + mb + r] = f2bf(acc[i][j][r] + bvv);
            }
        }
        __syncthreads();
        const int btok = m0 >> 11;
        const int s0 = m0 & (S_ - 1);
        const int half = seg & 1;
#pragma unroll
        for (int it = 0; it < 16; it++) {
            int n_local = it * 8 + w * 2 + (seg >> 1);
            int n = n0 + n_local;
            int h = n >> 6, d = n & 63;
            u16x4 v = *(const u16x4*)&Cs[n_local * 132 + half * 64 + l16 * 4];
            *(u16x4*)&Vo[(((size_t)btok * H_ + h) * D_ + d) * S_ + s0 + half * 64 + l16 * 4] = v;
        }
    }
}

// ---------------- Kernel 2: attention (no-max softmax, flash-style) ---------
__global__ __launch_bounds__(256, 2) void attn_kernel(
    const unsigned short* __restrict__ Q, const unsigned short* __restrict__ K,
    const unsigned short* __restrict__ Vt, unsigned short* __restrict__ ctx)
{
    __shared__ unsigned short Ks[2][64 * 32];
    __shared__ unsigned short Vs[2][64 * 32];
    __shared__ unsigned short Ps[4][32 * 72];
    const int t = threadIdx.x;
    const int w = t >> 6, lane = t & 63, quad = lane >> 4, l16 = lane & 15;
    const int bh = blockIdx.y;
    const int q0 = blockIdx.x * 128 + w * 32;

    const unsigned short* Qg = Q + ((size_t)bh * S_ + q0) * D_;
    bf16x8 qf[2][2];
#pragma unroll
    for (int i = 0; i < 2; i++)
#pragma unroll
        for (int ks = 0; ks < 2; ks++)
            qf[i][ks] = *(const bf16x8*)(Qg + (i * 16 + l16) * 64 + ks * 32 + quad * 8);

    bf16x8 ones;
#pragma unroll
    for (int e = 0; e < 8; e++) ones[e] = (short)0x3F80;

    f32x4 zero = {0.f, 0.f, 0.f, 0.f};
    f32x4 acc_o[2][4];
    f32x4 acc_l[2];
#pragma unroll
    for (int i = 0; i < 2; i++) {
        acc_l[i] = zero;
#pragma unroll
        for (int j = 0; j < 4; j++) acc_o[i][j] = zero;
    }

    const int r4 = t >> 2, c8v = (t & 3) * 8;
    const unsigned short* Kg0 = K + (size_t)bh * S_ * D_;
    const unsigned short* Vg0 = Vt + (size_t)bh * D_ * S_;

    for (int kt = 0; kt < S_; kt += 64) {
        const unsigned short* Kg = Kg0 + (size_t)(kt + r4) * 64 + c8v;
        const unsigned short* Vg = Vg0 + (size_t)r4 * S_ + kt + c8v;
        bf16x8 k0 = *(const bf16x8*)(Kg);
        bf16x8 k1 = *(const bf16x8*)(Kg + 32);
        bf16x8 v0 = *(const bf16x8*)(Vg);
        bf16x8 v1 = *(const bf16x8*)(Vg + 32);
        __syncthreads();
        *(bf16x8*)&Ks[0][t * 8] = k0;
        *(bf16x8*)&Ks[1][t * 8] = k1;
        *(bf16x8*)&Vs[0][t * 8] = v0;
        *(bf16x8*)&Vs[1][t * 8] = v1;
        __syncthreads();

        f32x4 sc[2][4];
#pragma unroll
        for (int i = 0; i < 2; i++)
#pragma unroll
            for (int j = 0; j < 4; j++) sc[i][j] = zero;
#pragma unroll
        for (int ks = 0; ks < 2; ks++) {
            bf16x8 kf[4];
#pragma unroll
            for (int j = 0; j < 4; j++)
                kf[j] = *(const bf16x8*)&Ks[ks][(j * 16 + l16) * 32 + quad * 8];
#pragma unroll
            for (int i = 0; i < 2; i++)
#pragma unroll
                for (int j = 0; j < 4; j++)
                    sc[i][j] = mfma16(qf[i][ks], kf[j], sc[i][j]);
        }
#pragma unroll
        for (int i = 0; i < 2; i++)
#pragma unroll
            for (int j = 0; j < 4; j++)
#pragma unroll
                for (int r = 0; r < 4; r++) {
                    float p = __expf(sc[i][j][r] * 0.125f);
                    Ps[w][(i * 16 + quad * 4 + r) * 72 + j * 16 + l16] = f2bf(p);
                }
        __syncthreads();
#pragma unroll
        for (int ks = 0; ks < 2; ks++) {
            bf16x8 pf[2], vf[4];
#pragma unroll
            for (int i = 0; i < 2; i++)
                pf[i] = *(const bf16x8*)&Ps[w][(i * 16 + l16) * 72 + ks * 32 + quad * 8];
#pragma unroll
            for (int jd = 0; jd < 4; jd++)
                vf[jd] = *(const bf16x8*)&Vs[ks][(jd * 16 + l16) * 32 + quad * 8];
#pragma unroll
            for (int i = 0; i < 2; i++) {
#pragma unroll
                for (int jd = 0; jd < 4; jd++)
                    acc_o[i][jd] = mfma16(pf[i], vf[jd], acc_o[i][jd]);
                acc_l[i] = mfma16(pf[i], ones, acc_l[i]);
            }
        }
    }

    const int b = bh >> 4, h = bh & 15;
#pragma unroll
    for (int i = 0; i < 2; i++) {
        f32x4 rl;
#pragma unroll
        for (int r = 0; r < 4; r++) rl[r] = 1.0f / acc_l[i][r];
#pragma unroll
        for (int jd = 0; jd < 4; jd++)
#pragma unroll
            for (int r = 0; r < 4; r++) {
                int qrow = q0 + i * 16 + quad * 4 + r;
                int col = h * 64 + jd * 16 + l16;
                ctx[((size_t)b * S_ + qrow) * E_ + col] = f2bf(acc_o[i][jd][r] * rl[r]);
            }
    }
}

// ---------------- Kernel 3: output projection (f32 W/bias, f32 out) ---------
__global__ __launch_bounds__(256, 2) void out_kernel(
    const unsigned short* __restrict__ Cx, const float* __restrict__ Wo,
    const float* __restrict__ bo, float* __restrict__ out)
{
    __shared__ unsigned short As[128 * 32];
    __shared__ unsigned short Bs[64 * 32];
    const int t = threadIdx.x;
    const int w = t >> 6, lane = t & 63, quad = lane >> 4, l16 = lane & 15;
    const int m0 = blockIdx.y * 128, n0 = blockIdx.x * 64;
    const int wr = w * 32;
    const int r4 = t >> 2, c8 = (t & 3) * 8;
    const unsigned short* Ag = Cx + (size_t)(m0 + r4) * E_ + c8;
    const float*          Bg = Wo + (size_t)(n0 + (r4 & 63)) * E_ + c8;

    f32x4 zero = {0.f, 0.f, 0.f, 0.f};
    f32x4 acc[2][4];
#pragma unroll
    for (int i = 0; i < 2; i++)
#pragma unroll
        for (int j = 0; j < 4; j++) acc[i][j] = zero;

    for (int kt = 0; kt < E_; kt += 32) {
        bf16x8 a0 = *(const bf16x8*)(Ag + kt);
        bf16x8 a1 = *(const bf16x8*)(Ag + 64 * E_ + kt);
        bf16x8 b0 = cvt8(Bg + kt);
        __syncthreads();
        *(bf16x8*)&As[t * 8]        = a0;
        *(bf16x8*)&As[t * 8 + 2048] = a1;
        *(bf16x8*)&Bs[t * 8]        = b0;
        __syncthreads();
        bf16x8 af[2], bfr[4];
#pragma unroll
        for (int i = 0; i < 2; i++)
            af[i] = *(const bf16x8*)&As[(wr + i * 16 + l16) * 32 + quad * 8];
#pragma unroll
        for (int j = 0; j < 4; j++)
            bfr[j] = *(const bf16x8*)&Bs[(j * 16 + l16) * 32 + quad * 8];
#pragma unroll
        for (int i = 0; i < 2; i++)
#pragma unroll
            for (int j = 0; j < 4; j++)
                acc[i][j] = mfma16(af[i], bfr[j], acc[i][j]);
    }

#pragma unroll
    for (int j = 0; j < 4; j++) {
        int n = n0 + j * 16 + l16;
        float bvv = bo[n];
#pragma unroll
        for (int i = 0; i < 2; i++) {
            int mrow = m0 + wr + i * 16 + quad * 4;
#pragma unroll
            for (int r = 0; r < 4; r++)
                out[(size_t)(mrow + r) * E_ + n] = acc[i][j][r] + bvv;
        }
    }
}

extern "C" void kernel_launch(void* const* d_in, const int* in_sizes, int n_in,
                              void* d_out, int out_size, void* d_ws, size_t ws_size,
                              hipStream_t stream) {
    const float* X  = (const float*)d_in[0];
    const float* Wq = (const float*)d_in[1];
    const float* bq = (const float*)d_in[2];
    const float* Wk = (const float*)d_in[3];
    const float* bk = (const float*)d_in[4];
    const float* Wv = (const float*)d_in[5];
    const float* bv = (const float*)d_in[6];
    const float* Wo = (const float*)d_in[7];
    const float* bo = (const float*)d_in[8];
    float* outp = (float*)d_out;

    const size_t TN = (size_t)B_ * H_ * S_ * D_;  // 4M elements
    if (ws_size < 4 * TN * sizeof(unsigned short)) return;

    unsigned short* Qb = (unsigned short*)d_ws;
    unsigned short* Kb = Qb + TN;
    unsigned short* Vb = Kb + TN;
    unsigned short* Cx = Vb + TN;

    qkv_rope_kernel<<<dim3(E_ / 128, M_ / 128, 3), 256, 0, stream>>>(
        X, Wq, Wk, Wv, bq, bk, bv, Qb, Kb, Vb);
    attn_kernel<<<dim3(S_ / 128, B_ * H_), 256, 0, stream>>>(Qb, Kb, Vb, Cx);
    out_kernel<<<dim3(E_ / 64, M_ / 128), 256, 0, stream>>>(Cx, Wo, bo, outp);
}